// Round 3
// baseline (15013.614 us; speedup 1.0000x reference)
//
#include <hip/hip_runtime.h>

// ---------------------------------------------------------------------------
// GNet: RevIN -> 2-layer GRU (B=128, L=512, H=512, I=96) -> proj -> RevIN^-1
// Persistent NON-cooperative kernel (256 blocks x 256 thr, guaranteed
// co-resident at 1 block/CU); custom sense-reversing grid barrier with
// agent-scope acquire/release atomics; weights in VGPRs as bf16 B-frags;
// 1 barrier per timestep (layer pipelining: cell0 computes h0(t) while
// cell1 computes h1(t-1)).
// R2 post-mortem: hipLaunchCooperativeKernel was rejected (needs 2 blk/CU at
// ~280 VGPR/wave -> validator says 1) and the error was unchecked -> rnn
// never ran (ys stayed 0xAA ~= 0 -> output = channel means, absmax 1.4165,
// bit-identical across rounds). Plain launch + own barrier fixes that.
// ---------------------------------------------------------------------------

typedef __attribute__((ext_vector_type(8))) __bf16 bf16x8;
typedef __attribute__((ext_vector_type(4))) float  f32x4;

constexpr int B_  = 128;
constexpr int L_  = 512;
constexpr int H_  = 512;
constexpr int CI_ = 96;    // 16 treat + 16 outcome + 64 covariate
constexpr float EPSR = 1e-5f;
constexpr unsigned NBLK = 256;

// ws layout (bytes)
constexpr size_t XN_OFF = 0;                                   // bf16 [L][B][96]
constexpr size_t XN_BYTES = (size_t)L_ * B_ * CI_ * 2;
constexpr size_t YS_OFF = XN_OFF + XN_BYTES;                   // bf16 [L][B][H]
constexpr size_t YS_BYTES = (size_t)L_ * B_ * H_ * 2;
constexpr size_t H0_OFF = YS_OFF + YS_BYTES;                   // bf16 [2][B][H]
constexpr size_t H0_BYTES = (size_t)2 * B_ * H_ * 2;
constexpr size_t BAR_OFF = H0_OFF + H0_BYTES;                  // 2 x u32 (+pad)
constexpr size_t BAR_BYTES = 128;
constexpr size_t ST_OFF = BAR_OFF + BAR_BYTES;                 // fp32 stats
// stats float offsets
constexpr int ST_TM = 0, ST_TSD = 2048, ST_OM = 4096, ST_OSD = 6144,
              ST_CM = 8192, ST_CSD = 16384;  // total 24576 floats

__device__ inline unsigned short f2bf(float f) {
  unsigned u = __builtin_bit_cast(unsigned, f);
  u += 0x7fffu + ((u >> 16) & 1u);
  return (unsigned short)(u >> 16);
}
__device__ inline float bf2f(unsigned short h) {
  unsigned u = ((unsigned)h) << 16;
  return __builtin_bit_cast(float, u);
}

union U16x8 { uint4 u4; unsigned short s[8]; bf16x8 v; };

__device__ inline bf16x8 load_bf8(const unsigned short* p) {
  U16x8 t; t.u4 = *(const uint4*)p; return t.v;
}
__device__ inline bf16x8 cvt_frag(const float* p) {  // 8 consecutive fp32 -> bf16x8
  U16x8 t;
  float4 a = *(const float4*)p;
  float4 b = *(const float4*)(p + 4);
  t.s[0] = f2bf(a.x); t.s[1] = f2bf(a.y); t.s[2] = f2bf(a.z); t.s[3] = f2bf(a.w);
  t.s[4] = f2bf(b.x); t.s[5] = f2bf(b.y); t.s[6] = f2bf(b.z); t.s[7] = f2bf(b.w);
  return t.v;
}
__device__ inline f32x4 mfma16(bf16x8 a, bf16x8 b, f32x4 c) {
  return __builtin_amdgcn_mfma_f32_16x16x32_bf16(a, b, c, 0, 0, 0);
}
__device__ inline float sigm(float x) {
  x = fminf(fmaxf(x, -30.f), 30.f);
  return 1.f / (1.f + __expf(-x));
}
__device__ inline float tanh_(float x) {
  x = fminf(fmaxf(x, -15.f), 15.f);
  float e = __expf(-2.f * x);
  return (1.f - e) / (1.f + e);
}

// Sense-reversing grid barrier, agent-scope acq/rel (L2 wb/inv on gfx950).
// All NBLK blocks must be co-resident (they are: 256 blocks, 1 block/CU).
__device__ inline void grid_bar(unsigned* cnt, unsigned* gen) {
  __syncthreads();  // drains each wave's vmem (compiler emits waitcnt)
  if (threadIdx.x == 0) {
    unsigned g = __hip_atomic_load(gen, __ATOMIC_RELAXED, __HIP_MEMORY_SCOPE_AGENT);
    unsigned old = __hip_atomic_fetch_add(cnt, 1u, __ATOMIC_ACQ_REL, __HIP_MEMORY_SCOPE_AGENT);
    if (old == NBLK - 1u) {
      __hip_atomic_store(cnt, 0u, __ATOMIC_RELAXED, __HIP_MEMORY_SCOPE_AGENT);
      __hip_atomic_store(gen, g + 1u, __ATOMIC_RELEASE, __HIP_MEMORY_SCOPE_AGENT);
    } else {
      unsigned cur;
      do {
        __builtin_amdgcn_s_sleep(1);
        cur = __hip_atomic_load(gen, __ATOMIC_ACQUIRE, __HIP_MEMORY_SCOPE_AGENT);
      } while (cur == g);
    }
  }
  __syncthreads();
}

// ---------------------------------------------------------------------------
// RevIN statistics: mean + std (ddof=1) per (batch, channel), two-pass.
// ---------------------------------------------------------------------------
__global__ void stats_kernel(const float* __restrict__ trt,
                             const float* __restrict__ outh,
                             const float* __restrict__ cov,
                             float* __restrict__ stats) {
  int b = blockIdx.x;
  int ch = threadIdx.x;
  if (ch >= 96) return;
  const float* p; int C; float* mdst; float* sdst; int si;
  if (ch < 16)      { p = trt  + (size_t)b * L_ * 16 + ch;        C = 16; mdst = stats + ST_TM; sdst = stats + ST_TSD; si = b * 16 + ch; }
  else if (ch < 32) { p = outh + (size_t)b * L_ * 16 + (ch - 16); C = 16; mdst = stats + ST_OM; sdst = stats + ST_OSD; si = b * 16 + ch - 16; }
  else              { p = cov  + (size_t)b * L_ * 64 + (ch - 32); C = 64; mdst = stats + ST_CM; sdst = stats + ST_CSD; si = b * 64 + ch - 32; }
  float s = 0.f;
  for (int t = 0; t < L_; ++t) s += p[(size_t)t * C];
  float m = s / (float)L_;
  float q = 0.f;
  for (int t = 0; t < L_; ++t) { float d = p[(size_t)t * C] - m; q += d * d; }
  float sd = sqrtf(q / (float)(L_ - 1));
  mdst[si] = m; sdst[si] = sd;
}

// ---------------------------------------------------------------------------
// Normalize + concat -> xn bf16, layout [t][b][c]
// ---------------------------------------------------------------------------
__global__ void norm_kernel(const float* __restrict__ trt,
                            const float* __restrict__ outh,
                            const float* __restrict__ cov,
                            const float* __restrict__ stats,
                            const float* __restrict__ w_t, const float* __restrict__ b_t,
                            const float* __restrict__ w_o, const float* __restrict__ b_o,
                            const float* __restrict__ w_c, const float* __restrict__ b_c,
                            unsigned short* __restrict__ xn) {
  int idx = blockIdx.x * 256 + threadIdx.x;  // < L*B*96
  int c = idx % CI_;
  int tb = idx / CI_;
  int b = tb % B_;
  int t = tb / B_;
  float v, m, sd, w, bb;
  if (c < 16) {
    v = trt[((size_t)b * L_ + t) * 16 + c];
    m = stats[ST_TM + b * 16 + c]; sd = stats[ST_TSD + b * 16 + c];
    w = w_t[c]; bb = b_t[c];
  } else if (c < 32) {
    int cc = c - 16;
    v = outh[((size_t)b * L_ + t) * 16 + cc];
    m = stats[ST_OM + b * 16 + cc]; sd = stats[ST_OSD + b * 16 + cc];
    w = w_o[cc]; bb = b_o[cc];
  } else {
    int cc = c - 32;
    v = cov[((size_t)b * L_ + t) * 64 + cc];
    m = stats[ST_CM + b * 64 + cc]; sd = stats[ST_CSD + b * 64 + cc];
    w = w_c[cc]; bb = b_c[cc];
  }
  xn[idx] = f2bf((v - m) / (sd + EPSR) * w + bb);
}

// ---------------------------------------------------------------------------
// Persistent GRU kernel. 256 blocks x 256 threads = 4 waves = 2 wave-pairs.
// Blocks [0,128): cell0 — pairs p=2*wg+sub, (u0,m0)=((p&31)*16,(p>>5)*16)
//   pair wave0 (GATES): gi (x@Wih0,K=96) + gh half (Whh0 k 0..255)
//   pair wave1:         gh half (Whh0 k 256..511) -> LDS
// Blocks [128,256): cell1
//   pair wave0 (GATES): gi (h0@Wih1, K=512)
//   pair wave1:         gh (h1@Whh1, K=512) -> LDS
// Phase t=1..513: cell0: h0(t)=cell(x_t, h0(t-1));
//                 cell1: h1(t-1)=cell(h0(t-1), h1(t-2)); one barrier/phase.
// ---------------------------------------------------------------------------
template <int ROLE, int NGI, int KI, int NGH, int CH0, bool GATES>
__device__ __forceinline__ void wave_run(
    unsigned* bcnt, unsigned* bgen,
    float (*exch)[64][4],
    int lane, int u0, int m0,
    const unsigned short* __restrict__ xn,
    unsigned short* __restrict__ ys,
    unsigned short* __restrict__ h0buf,
    const float* __restrict__ WI, const float* __restrict__ WH,
    const float* __restrict__ bi, const float* __restrict__ bh) {
  const int quad = lane >> 4;
  const int l16 = lane & 15;
  const int b = m0 + l16;      // A-fragment row (batch)
  const int urow = u0 + l16;   // weight row within gate block / output column

  bf16x8 BGI[3][NGI > 0 ? NGI : 1];
  bf16x8 BGH[3][NGH > 0 ? NGH : 1];
  if (NGI > 0) {
#pragma unroll
    for (int g = 0; g < 3; ++g)
#pragma unroll
      for (int c = 0; c < NGI; ++c)
        BGI[g][c] = cvt_frag(WI + (size_t)(g * H_ + urow) * KI + 32 * c + quad * 8);
  }
  if (NGH > 0) {
#pragma unroll
    for (int g = 0; g < 3; ++g)
#pragma unroll
      for (int c = 0; c < NGH; ++c)
        BGH[g][c] = cvt_frag(WH + (size_t)(g * H_ + urow) * H_ + 32 * (CH0 + c) + quad * 8);
  }
  float bi_[3] = {0.f, 0.f, 0.f}, bh_[3] = {0.f, 0.f, 0.f};
  if (GATES) {
#pragma unroll
    for (int g = 0; g < 3; ++g) { bi_[g] = bi[g * H_ + urow]; bh_[g] = bh[g * H_ + urow]; }
  }

  for (int t = 1; t <= 513; ++t) {
    const bool active = (ROLE == 0) ? (t <= 512) : (t >= 2);
    f32x4 agi[3], agh[3];
#pragma unroll
    for (int g = 0; g < 3; ++g) {
      agi[g] = (f32x4){0.f, 0.f, 0.f, 0.f};
      agh[g] = (f32x4){0.f, 0.f, 0.f, 0.f};
    }
    if (active) {
      if (NGI > 0) {
        const unsigned short* Agi = (ROLE == 0)
            ? xn + ((size_t)(t - 1) * B_ + b) * CI_
            : h0buf + (size_t)((t - 1) & 1) * B_ * H_ + (size_t)b * H_;
#pragma unroll
        for (int c = 0; c < NGI; ++c) {
          bf16x8 a = load_bf8(Agi + 32 * c + quad * 8);
          agi[0] = mfma16(a, BGI[0][c], agi[0]);
          agi[1] = mfma16(a, BGI[1][c], agi[1]);
          agi[2] = mfma16(a, BGI[2][c], agi[2]);
        }
      }
      if (NGH > 0) {
        bool gh_ok = (ROLE == 0) || (t >= 3);
        if (gh_ok) {
          const unsigned short* Agh = (ROLE == 0)
              ? h0buf + (size_t)((t - 1) & 1) * B_ * H_ + (size_t)b * H_
              : ys + (size_t)(t - 3) * B_ * H_ + (size_t)b * H_;
#pragma unroll
          for (int c = 0; c < NGH; ++c) {
            bf16x8 a = load_bf8(Agh + 32 * (CH0 + c) + quad * 8);
            agh[0] = mfma16(a, BGH[0][c], agh[0]);
            agh[1] = mfma16(a, BGH[1][c], agh[1]);
            agh[2] = mfma16(a, BGH[2][c], agh[2]);
          }
        }
      }
    }
    if (!GATES) {
      // producer wave: publish gh partials to LDS (zeros when inactive)
#pragma unroll
      for (int g = 0; g < 3; ++g)
#pragma unroll
        for (int r = 0; r < 4; ++r) exch[g][lane][r] = agh[g][r];
      __syncthreads();
    } else {
      __syncthreads();
      if (active) {
#pragma unroll
        for (int g = 0; g < 3; ++g)
#pragma unroll
          for (int r = 0; r < 4; ++r) agh[g][r] += exch[g][lane][r];
        const unsigned short* prevp = (ROLE == 0)
            ? h0buf + (size_t)((t - 1) & 1) * B_ * H_
            : (t >= 3 ? ys + (size_t)(t - 3) * B_ * H_ : (const unsigned short*)nullptr);
        unsigned short* outp = (ROLE == 0)
            ? h0buf + (size_t)(t & 1) * B_ * H_
            : ys + (size_t)(t - 2) * B_ * H_;
#pragma unroll
        for (int r = 0; r < 4; ++r) {
          int br = m0 + quad * 4 + r;
          float rr = sigm(agi[0][r] + bi_[0] + agh[0][r] + bh_[0]);
          float zz = sigm(agi[1][r] + bi_[1] + agh[1][r] + bh_[1]);
          float nn = tanh_(agi[2][r] + bi_[2] + rr * (agh[2][r] + bh_[2]));
          float hp = prevp ? bf2f(prevp[(size_t)br * H_ + urow]) : 0.f;
          float hv = (1.f - zz) * nn + zz * hp;
          outp[(size_t)br * H_ + urow] = f2bf(hv);
        }
      }
    }
    grid_bar(bcnt, bgen);  // release stores / barrier / acquire, whole block
  }
}

__launch_bounds__(256, 1)
__global__ void rnn_kernel(const unsigned short* __restrict__ xn,
                           unsigned short* __restrict__ ys,
                           unsigned short* __restrict__ h0buf,
                           unsigned* __restrict__ bar,
                           const float* __restrict__ Wih0, const float* __restrict__ Whh0,
                           const float* __restrict__ bih0, const float* __restrict__ bhh0,
                           const float* __restrict__ Wih1, const float* __restrict__ Whh1,
                           const float* __restrict__ bih1, const float* __restrict__ bhh1) {
  __shared__ float exch[2][3][64][4];

  unsigned* bcnt = bar;
  unsigned* bgen = bar + 1;
  const int wg = blockIdx.x;
  const int wave = threadIdx.x >> 6;
  const int lane = threadIdx.x & 63;
  const int sub = wave >> 1;   // which wave-pair in this block
  const int wr = wave & 1;     // 0 = GATES consumer, 1 = producer

  if (wg < 128) {
    int pair = wg * 2 + sub;
    int u0 = (pair & 31) * 16;
    int m0 = (pair >> 5) * 16;
    if (wr == 0)
      wave_run<0, 3, CI_, 8, 0, true>(bcnt, bgen, exch[sub], lane, u0, m0,
                                      xn, ys, h0buf, Wih0, Whh0, bih0, bhh0);
    else
      wave_run<0, 0, CI_, 8, 8, false>(bcnt, bgen, exch[sub], lane, u0, m0,
                                       xn, ys, h0buf, Wih0, Whh0, bih0, bhh0);
  } else {
    int pair = (wg - 128) * 2 + sub;
    int u0 = (pair & 31) * 16;
    int m0 = (pair >> 5) * 16;
    if (wr == 0)
      wave_run<1, 16, H_, 0, 0, true>(bcnt, bgen, exch[sub], lane, u0, m0,
                                      xn, ys, h0buf, Wih1, Whh1, bih1, bhh1);
    else
      wave_run<1, 0, H_, 16, 0, false>(bcnt, bgen, exch[sub], lane, u0, m0,
                                       xn, ys, h0buf, Wih1, Whh1, bih1, bhh1);
  }
}

// ---------------------------------------------------------------------------
// Output projection (65536 x 80, K=512) + inverse RevIN, MFMA.
// grid = 512 m-chunks * 5 n-tiles = 2560 blocks x 64 threads (1 wave).
// ---------------------------------------------------------------------------
__global__ void out_kernel(const unsigned short* __restrict__ ys,
                           const float* __restrict__ Wout, const float* __restrict__ bout,
                           const float* __restrict__ w_o, const float* __restrict__ b_o,
                           const float* __restrict__ w_c, const float* __restrict__ b_c,
                           const float* __restrict__ stats,
                           float* __restrict__ dout) {
  int lane = threadIdx.x;
  int quad = lane >> 4, l16 = lane & 15;
  int nb = blockIdx.x % 5, mc = blockIdx.x / 5;
  int ch = nb * 16 + l16;

  bf16x8 BW[16];
#pragma unroll
  for (int c = 0; c < 16; ++c)
    BW[c] = cvt_frag(Wout + (size_t)ch * 512 + 32 * c + quad * 8);
  float bo = bout[ch];
  float rb, rw; const float* mm; const float* ss; int cs, cidx;
  if (ch < 16) { rb = b_o[ch]; rw = w_o[ch]; mm = stats + ST_OM; ss = stats + ST_OSD; cs = 16; cidx = ch; }
  else         { rb = b_c[ch - 16]; rw = w_c[ch - 16]; mm = stats + ST_CM; ss = stats + ST_CSD; cs = 64; cidx = ch - 16; }

  for (int i = 0; i < 8; ++i) {
    int mt = mc * 8 + i;
    const unsigned short* A = ys + (size_t)(mt * 16 + l16) * 512;
    f32x4 acc = {0.f, 0.f, 0.f, 0.f};
#pragma unroll
    for (int c = 0; c < 16; ++c)
      acc = mfma16(load_bf8(A + 32 * c + quad * 8), BW[c], acc);
#pragma unroll
    for (int r = 0; r < 4; ++r) {
      int rr = mt * 16 + quad * 4 + r;
      int t = rr >> 7;
      int b = rr & 127;
      float m = mm[b * cs + cidx], sd = ss[b * cs + cidx];
      float v = (acc[r] + bo - rb) / rw * (sd + EPSR) + m;
      size_t off = (ch < 16)
          ? ((size_t)b * 8192 + (size_t)t * 16 + ch)
          : ((size_t)1048576 + (size_t)b * 32768 + (size_t)t * 64 + (ch - 16));
      dout[off] = v;
    }
  }
}

// ---------------------------------------------------------------------------
extern "C" void kernel_launch(void* const* d_in, const int* in_sizes, int n_in,
                              void* d_out, int out_size, void* d_ws, size_t ws_size,
                              hipStream_t stream) {
  const float* cov  = (const float*)d_in[0];
  const float* trt  = (const float*)d_in[1];
  const float* outh = (const float*)d_in[2];
  const float* Wih0 = (const float*)d_in[3];
  const float* Whh0 = (const float*)d_in[4];
  const float* bih0 = (const float*)d_in[5];
  const float* bhh0 = (const float*)d_in[6];
  const float* Wih1 = (const float*)d_in[7];
  const float* Whh1 = (const float*)d_in[8];
  const float* bih1 = (const float*)d_in[9];
  const float* bhh1 = (const float*)d_in[10];
  const float* Wout = (const float*)d_in[11];
  const float* bout = (const float*)d_in[12];
  const float* w_t  = (const float*)d_in[13];
  const float* b_t  = (const float*)d_in[14];
  const float* w_o  = (const float*)d_in[15];
  const float* b_o  = (const float*)d_in[16];
  const float* w_c  = (const float*)d_in[17];
  const float* b_c  = (const float*)d_in[18];

  char* ws = (char*)d_ws;
  unsigned short* xn = (unsigned short*)(ws + XN_OFF);
  unsigned short* ys = (unsigned short*)(ws + YS_OFF);
  unsigned short* h0 = (unsigned short*)(ws + H0_OFF);
  unsigned* bar = (unsigned*)(ws + BAR_OFF);
  float* stats = (float*)(ws + ST_OFF);

  // ws is re-poisoned to 0xAA before every launch: zero h0 state + barrier.
  hipMemsetAsync((void*)(ws + H0_OFF), 0, H0_BYTES + BAR_BYTES, stream);

  stats_kernel<<<128, 128, 0, stream>>>(trt, outh, cov, stats);
  norm_kernel<<<(L_ * B_ * CI_) / 256, 256, 0, stream>>>(
      trt, outh, cov, stats, w_t, b_t, w_o, b_o, w_c, b_c, xn);

  rnn_kernel<<<NBLK, 256, 0, stream>>>(xn, ys, h0, bar,
                                       Wih0, Whh0, bih0, bhh0,
                                       Wih1, Whh1, bih1, bhh1);

  out_kernel<<<2560, 64, 0, stream>>>(ys, Wout, bout, w_o, b_o, w_c, b_c,
                                      stats, (float*)d_out);
}

// Round 4
// 5936.179 us; speedup vs baseline: 2.5292x; 2.5292x over previous
//
#include <hip/hip_runtime.h>

// ---------------------------------------------------------------------------
// GNet: RevIN -> 2-layer GRU (B=128, L=512, H=512, I=96) -> proj -> RevIN^-1
// Persistent NON-cooperative kernel (256 blocks x 256 thr, 1 block/CU);
// weights in VGPRs as bf16 MFMA B-frags; 1 barrier per timestep.
// R3 post-mortem: 28 us/phase. Cause: ACQUIRE load in the spin loop emits
// buffer_inv (L1+L2 invalidate) per poll -> 255 blocks thrash every XCD's L2
// -> FETCH_SIZE 584 MB, latency-bound refetch. Plus one global 256-block
// barrier convoys all XCDs.
// R4 fix: (a) relaxed spin + single acquire fence at exit; (b) partition by
// batch into 8 independent groups (blockIdx%8), each with its own
// 32-participant barrier + sequential chain (XCD-local by the %8 round-robin
// heuristic; correctness placement-independent).
// ---------------------------------------------------------------------------

typedef __attribute__((ext_vector_type(8))) __bf16 bf16x8;
typedef __attribute__((ext_vector_type(4))) float  f32x4;

constexpr int B_  = 128;
constexpr int L_  = 512;
constexpr int H_  = 512;
constexpr int CI_ = 96;    // 16 treat + 16 outcome + 64 covariate
constexpr float EPSR = 1e-5f;
constexpr unsigned GRP_BLKS = 32;   // blocks per sync group

// ws layout (bytes)
constexpr size_t XN_OFF = 0;                                   // bf16 [L][B][96]
constexpr size_t XN_BYTES = (size_t)L_ * B_ * CI_ * 2;
constexpr size_t YS_OFF = XN_OFF + XN_BYTES;                   // bf16 [L][B][H]
constexpr size_t YS_BYTES = (size_t)L_ * B_ * H_ * 2;
constexpr size_t H0_OFF = YS_OFF + YS_BYTES;                   // bf16 [2][B][H]
constexpr size_t H0_BYTES = (size_t)2 * B_ * H_ * 2;
constexpr size_t BAR_OFF = H0_OFF + H0_BYTES;                  // 8 groups x 128B
constexpr size_t BAR_BYTES = 8 * 128;
constexpr size_t ST_OFF = BAR_OFF + BAR_BYTES;                 // fp32 stats
// stats float offsets
constexpr int ST_TM = 0, ST_TSD = 2048, ST_OM = 4096, ST_OSD = 6144,
              ST_CM = 8192, ST_CSD = 16384;  // total 24576 floats

__device__ inline unsigned short f2bf(float f) {
  unsigned u = __builtin_bit_cast(unsigned, f);
  u += 0x7fffu + ((u >> 16) & 1u);
  return (unsigned short)(u >> 16);
}
__device__ inline float bf2f(unsigned short h) {
  unsigned u = ((unsigned)h) << 16;
  return __builtin_bit_cast(float, u);
}

union U16x8 { uint4 u4; unsigned short s[8]; bf16x8 v; };

__device__ inline bf16x8 load_bf8(const unsigned short* p) {
  U16x8 t; t.u4 = *(const uint4*)p; return t.v;
}
__device__ inline bf16x8 cvt_frag(const float* p) {  // 8 consecutive fp32 -> bf16x8
  U16x8 t;
  float4 a = *(const float4*)p;
  float4 b = *(const float4*)(p + 4);
  t.s[0] = f2bf(a.x); t.s[1] = f2bf(a.y); t.s[2] = f2bf(a.z); t.s[3] = f2bf(a.w);
  t.s[4] = f2bf(b.x); t.s[5] = f2bf(b.y); t.s[6] = f2bf(b.z); t.s[7] = f2bf(b.w);
  return t.v;
}
__device__ inline f32x4 mfma16(bf16x8 a, bf16x8 b, f32x4 c) {
  return __builtin_amdgcn_mfma_f32_16x16x32_bf16(a, b, c, 0, 0, 0);
}
__device__ inline float sigm(float x) {
  x = fminf(fmaxf(x, -30.f), 30.f);
  return 1.f / (1.f + __expf(-x));
}
__device__ inline float tanh_(float x) {
  x = fminf(fmaxf(x, -15.f), 15.f);
  float e = __expf(-2.f * x);
  return (1.f - e) / (1.f + e);
}

// Sense-reversing group barrier (GRP_BLKS participants).
// Arrival: ACQ_REL fetch_add releases this block's prior stores (agent scope).
// Spin: RELAXED loads (no per-poll cache invalidate!); one ACQUIRE fence on
// exit makes peers' stores visible (buffer_inv, per-CU L1 + per-XCD L2).
__device__ inline void group_bar(unsigned* cnt, unsigned* gen) {
  __syncthreads();
  if (threadIdx.x == 0) {
    unsigned g = __hip_atomic_load(gen, __ATOMIC_RELAXED, __HIP_MEMORY_SCOPE_AGENT);
    unsigned old = __hip_atomic_fetch_add(cnt, 1u, __ATOMIC_ACQ_REL, __HIP_MEMORY_SCOPE_AGENT);
    if (old == GRP_BLKS - 1u) {
      __hip_atomic_store(cnt, 0u, __ATOMIC_RELAXED, __HIP_MEMORY_SCOPE_AGENT);
      __hip_atomic_store(gen, g + 1u, __ATOMIC_RELEASE, __HIP_MEMORY_SCOPE_AGENT);
    } else {
      unsigned cur;
      do {
        __builtin_amdgcn_s_sleep(1);
        cur = __hip_atomic_load(gen, __ATOMIC_RELAXED, __HIP_MEMORY_SCOPE_AGENT);
      } while (cur == g);
      __builtin_amdgcn_fence(__ATOMIC_ACQUIRE, "agent");
    }
  }
  __syncthreads();
}

// ---------------------------------------------------------------------------
// RevIN statistics: mean + std (ddof=1) per (batch, channel), two-pass.
// ---------------------------------------------------------------------------
__global__ void stats_kernel(const float* __restrict__ trt,
                             const float* __restrict__ outh,
                             const float* __restrict__ cov,
                             float* __restrict__ stats) {
  int b = blockIdx.x;
  int ch = threadIdx.x;
  if (ch >= 96) return;
  const float* p; int C; float* mdst; float* sdst; int si;
  if (ch < 16)      { p = trt  + (size_t)b * L_ * 16 + ch;        C = 16; mdst = stats + ST_TM; sdst = stats + ST_TSD; si = b * 16 + ch; }
  else if (ch < 32) { p = outh + (size_t)b * L_ * 16 + (ch - 16); C = 16; mdst = stats + ST_OM; sdst = stats + ST_OSD; si = b * 16 + ch - 16; }
  else              { p = cov  + (size_t)b * L_ * 64 + (ch - 32); C = 64; mdst = stats + ST_CM; sdst = stats + ST_CSD; si = b * 64 + ch - 32; }
  float s = 0.f;
  for (int t = 0; t < L_; ++t) s += p[(size_t)t * C];
  float m = s / (float)L_;
  float q = 0.f;
  for (int t = 0; t < L_; ++t) { float d = p[(size_t)t * C] - m; q += d * d; }
  float sd = sqrtf(q / (float)(L_ - 1));
  mdst[si] = m; sdst[si] = sd;
}

// ---------------------------------------------------------------------------
// Normalize + concat -> xn bf16, layout [t][b][c]
// ---------------------------------------------------------------------------
__global__ void norm_kernel(const float* __restrict__ trt,
                            const float* __restrict__ outh,
                            const float* __restrict__ cov,
                            const float* __restrict__ stats,
                            const float* __restrict__ w_t, const float* __restrict__ b_t,
                            const float* __restrict__ w_o, const float* __restrict__ b_o,
                            const float* __restrict__ w_c, const float* __restrict__ b_c,
                            unsigned short* __restrict__ xn) {
  int idx = blockIdx.x * 256 + threadIdx.x;  // < L*B*96
  int c = idx % CI_;
  int tb = idx / CI_;
  int b = tb % B_;
  int t = tb / B_;
  float v, m, sd, w, bb;
  if (c < 16) {
    v = trt[((size_t)b * L_ + t) * 16 + c];
    m = stats[ST_TM + b * 16 + c]; sd = stats[ST_TSD + b * 16 + c];
    w = w_t[c]; bb = b_t[c];
  } else if (c < 32) {
    int cc = c - 16;
    v = outh[((size_t)b * L_ + t) * 16 + cc];
    m = stats[ST_OM + b * 16 + cc]; sd = stats[ST_OSD + b * 16 + cc];
    w = w_o[cc]; bb = b_o[cc];
  } else {
    int cc = c - 32;
    v = cov[((size_t)b * L_ + t) * 64 + cc];
    m = stats[ST_CM + b * 64 + cc]; sd = stats[ST_CSD + b * 64 + cc];
    w = w_c[cc]; bb = b_c[cc];
  }
  xn[idx] = f2bf((v - m) / (sd + EPSR) * w + bb);
}

// ---------------------------------------------------------------------------
// Persistent GRU kernel. 256 blocks x 256 threads = 4 waves = 2 wave-pairs.
// Sync group g = blockIdx%8 owns batch tile m0 = g*16 (16 samples) and has
// its own barrier + chain. Within group: idx = blockIdx>>3 (0..31);
//   idx<16  -> cell0, pairs u-tile = idx*2+sub (u0 = tile*16)
//   idx>=16 -> cell1, pairs u-tile = (idx-16)*2+sub
// Pair wave0 (GATES) / wave1 (producer) split as before.
// Phase t=1..513: cell0: h0(t)=cell(x_t, h0(t-1));
//                 cell1: h1(t-1)=cell(h0(t-1), h1(t-2)); one group barrier.
// ---------------------------------------------------------------------------
template <int ROLE, int NGI, int KI, int NGH, int CH0, bool GATES>
__device__ __forceinline__ void wave_run(
    unsigned* bcnt, unsigned* bgen,
    float (*exch)[64][4],
    int lane, int u0, int m0,
    const unsigned short* __restrict__ xn,
    unsigned short* __restrict__ ys,
    unsigned short* __restrict__ h0buf,
    const float* __restrict__ WI, const float* __restrict__ WH,
    const float* __restrict__ bi, const float* __restrict__ bh) {
  const int quad = lane >> 4;
  const int l16 = lane & 15;
  const int b = m0 + l16;      // A-fragment row (batch)
  const int urow = u0 + l16;   // weight row within gate block / output column

  bf16x8 BGI[3][NGI > 0 ? NGI : 1];
  bf16x8 BGH[3][NGH > 0 ? NGH : 1];
  if (NGI > 0) {
#pragma unroll
    for (int g = 0; g < 3; ++g)
#pragma unroll
      for (int c = 0; c < NGI; ++c)
        BGI[g][c] = cvt_frag(WI + (size_t)(g * H_ + urow) * KI + 32 * c + quad * 8);
  }
  if (NGH > 0) {
#pragma unroll
    for (int g = 0; g < 3; ++g)
#pragma unroll
      for (int c = 0; c < NGH; ++c)
        BGH[g][c] = cvt_frag(WH + (size_t)(g * H_ + urow) * H_ + 32 * (CH0 + c) + quad * 8);
  }
  float bi_[3] = {0.f, 0.f, 0.f}, bh_[3] = {0.f, 0.f, 0.f};
  if (GATES) {
#pragma unroll
    for (int g = 0; g < 3; ++g) { bi_[g] = bi[g * H_ + urow]; bh_[g] = bh[g * H_ + urow]; }
  }

  for (int t = 1; t <= 513; ++t) {
    const bool active = (ROLE == 0) ? (t <= 512) : (t >= 2);
    f32x4 agi[3], agh[3];
#pragma unroll
    for (int g = 0; g < 3; ++g) {
      agi[g] = (f32x4){0.f, 0.f, 0.f, 0.f};
      agh[g] = (f32x4){0.f, 0.f, 0.f, 0.f};
    }
    if (active) {
      if (NGI > 0) {
        const unsigned short* Agi = (ROLE == 0)
            ? xn + ((size_t)(t - 1) * B_ + b) * CI_
            : h0buf + (size_t)((t - 1) & 1) * B_ * H_ + (size_t)b * H_;
#pragma unroll
        for (int c = 0; c < NGI; ++c) {
          bf16x8 a = load_bf8(Agi + 32 * c + quad * 8);
          agi[0] = mfma16(a, BGI[0][c], agi[0]);
          agi[1] = mfma16(a, BGI[1][c], agi[1]);
          agi[2] = mfma16(a, BGI[2][c], agi[2]);
        }
      }
      if (NGH > 0) {
        bool gh_ok = (ROLE == 0) || (t >= 3);
        if (gh_ok) {
          const unsigned short* Agh = (ROLE == 0)
              ? h0buf + (size_t)((t - 1) & 1) * B_ * H_ + (size_t)b * H_
              : ys + (size_t)(t - 3) * B_ * H_ + (size_t)b * H_;
#pragma unroll
          for (int c = 0; c < NGH; ++c) {
            bf16x8 a = load_bf8(Agh + 32 * (CH0 + c) + quad * 8);
            agh[0] = mfma16(a, BGH[0][c], agh[0]);
            agh[1] = mfma16(a, BGH[1][c], agh[1]);
            agh[2] = mfma16(a, BGH[2][c], agh[2]);
          }
        }
      }
    }
    if (!GATES) {
      // producer wave: publish gh partials to LDS (zeros when inactive)
#pragma unroll
      for (int g = 0; g < 3; ++g)
#pragma unroll
        for (int r = 0; r < 4; ++r) exch[g][lane][r] = agh[g][r];
      __syncthreads();
    } else {
      __syncthreads();
      if (active) {
#pragma unroll
        for (int g = 0; g < 3; ++g)
#pragma unroll
          for (int r = 0; r < 4; ++r) agh[g][r] += exch[g][lane][r];
        const unsigned short* prevp = (ROLE == 0)
            ? h0buf + (size_t)((t - 1) & 1) * B_ * H_
            : (t >= 3 ? ys + (size_t)(t - 3) * B_ * H_ : (const unsigned short*)nullptr);
        unsigned short* outp = (ROLE == 0)
            ? h0buf + (size_t)(t & 1) * B_ * H_
            : ys + (size_t)(t - 2) * B_ * H_;
#pragma unroll
        for (int r = 0; r < 4; ++r) {
          int br = m0 + quad * 4 + r;
          float rr = sigm(agi[0][r] + bi_[0] + agh[0][r] + bh_[0]);
          float zz = sigm(agi[1][r] + bi_[1] + agh[1][r] + bh_[1]);
          float nn = tanh_(agi[2][r] + bi_[2] + rr * (agh[2][r] + bh_[2]));
          float hp = prevp ? bf2f(prevp[(size_t)br * H_ + urow]) : 0.f;
          float hv = (1.f - zz) * nn + zz * hp;
          outp[(size_t)br * H_ + urow] = f2bf(hv);
        }
      }
    }
    group_bar(bcnt, bgen);
  }
}

__launch_bounds__(256, 1)
__global__ void rnn_kernel(const unsigned short* __restrict__ xn,
                           unsigned short* __restrict__ ys,
                           unsigned short* __restrict__ h0buf,
                           unsigned* __restrict__ bar,
                           const float* __restrict__ Wih0, const float* __restrict__ Whh0,
                           const float* __restrict__ bih0, const float* __restrict__ bhh0,
                           const float* __restrict__ Wih1, const float* __restrict__ Whh1,
                           const float* __restrict__ bih1, const float* __restrict__ bhh1) {
  __shared__ float exch[2][3][64][4];

  const int grp = blockIdx.x & 7;        // batch-tile / sync group (XCD-local)
  const int idx = blockIdx.x >> 3;       // 0..31 within group
  unsigned* bcnt = bar + grp * 32;       // 128B per group
  unsigned* bgen = bcnt + 1;
  const int m0 = grp * 16;

  const int wave = threadIdx.x >> 6;
  const int lane = threadIdx.x & 63;
  const int sub = wave >> 1;   // which wave-pair in this block
  const int wr = wave & 1;     // 0 = GATES consumer, 1 = producer

  if (idx < 16) {
    int u0 = (idx * 2 + sub) * 16;
    if (wr == 0)
      wave_run<0, 3, CI_, 8, 0, true>(bcnt, bgen, exch[sub], lane, u0, m0,
                                      xn, ys, h0buf, Wih0, Whh0, bih0, bhh0);
    else
      wave_run<0, 0, CI_, 8, 8, false>(bcnt, bgen, exch[sub], lane, u0, m0,
                                       xn, ys, h0buf, Wih0, Whh0, bih0, bhh0);
  } else {
    int u0 = ((idx - 16) * 2 + sub) * 16;
    if (wr == 0)
      wave_run<1, 16, H_, 0, 0, true>(bcnt, bgen, exch[sub], lane, u0, m0,
                                      xn, ys, h0buf, Wih1, Whh1, bih1, bhh1);
    else
      wave_run<1, 0, H_, 16, 0, false>(bcnt, bgen, exch[sub], lane, u0, m0,
                                       xn, ys, h0buf, Wih1, Whh1, bih1, bhh1);
  }
}

// ---------------------------------------------------------------------------
// Output projection (65536 x 80, K=512) + inverse RevIN, MFMA.
// grid = 512 m-chunks * 5 n-tiles = 2560 blocks x 64 threads (1 wave).
// ---------------------------------------------------------------------------
__global__ void out_kernel(const unsigned short* __restrict__ ys,
                           const float* __restrict__ Wout, const float* __restrict__ bout,
                           const float* __restrict__ w_o, const float* __restrict__ b_o,
                           const float* __restrict__ w_c, const float* __restrict__ b_c,
                           const float* __restrict__ stats,
                           float* __restrict__ dout) {
  int lane = threadIdx.x;
  int quad = lane >> 4, l16 = lane & 15;
  int nb = blockIdx.x % 5, mc = blockIdx.x / 5;
  int ch = nb * 16 + l16;

  bf16x8 BW[16];
#pragma unroll
  for (int c = 0; c < 16; ++c)
    BW[c] = cvt_frag(Wout + (size_t)ch * 512 + 32 * c + quad * 8);
  float bo = bout[ch];
  float rb, rw; const float* mm; const float* ss; int cs, cidx;
  if (ch < 16) { rb = b_o[ch]; rw = w_o[ch]; mm = stats + ST_OM; ss = stats + ST_OSD; cs = 16; cidx = ch; }
  else         { rb = b_c[ch - 16]; rw = w_c[ch - 16]; mm = stats + ST_CM; ss = stats + ST_CSD; cs = 64; cidx = ch - 16; }

  for (int i = 0; i < 8; ++i) {
    int mt = mc * 8 + i;
    const unsigned short* A = ys + (size_t)(mt * 16 + l16) * 512;
    f32x4 acc = {0.f, 0.f, 0.f, 0.f};
#pragma unroll
    for (int c = 0; c < 16; ++c)
      acc = mfma16(load_bf8(A + 32 * c + quad * 8), BW[c], acc);
#pragma unroll
    for (int r = 0; r < 4; ++r) {
      int rr = mt * 16 + quad * 4 + r;
      int t = rr >> 7;
      int b = rr & 127;
      float m = mm[b * cs + cidx], sd = ss[b * cs + cidx];
      float v = (acc[r] + bo - rb) / rw * (sd + EPSR) + m;
      size_t off = (ch < 16)
          ? ((size_t)b * 8192 + (size_t)t * 16 + ch)
          : ((size_t)1048576 + (size_t)b * 32768 + (size_t)t * 64 + (ch - 16));
      dout[off] = v;
    }
  }
}

// ---------------------------------------------------------------------------
extern "C" void kernel_launch(void* const* d_in, const int* in_sizes, int n_in,
                              void* d_out, int out_size, void* d_ws, size_t ws_size,
                              hipStream_t stream) {
  const float* cov  = (const float*)d_in[0];
  const float* trt  = (const float*)d_in[1];
  const float* outh = (const float*)d_in[2];
  const float* Wih0 = (const float*)d_in[3];
  const float* Whh0 = (const float*)d_in[4];
  const float* bih0 = (const float*)d_in[5];
  const float* bhh0 = (const float*)d_in[6];
  const float* Wih1 = (const float*)d_in[7];
  const float* Whh1 = (const float*)d_in[8];
  const float* bih1 = (const float*)d_in[9];
  const float* bhh1 = (const float*)d_in[10];
  const float* Wout = (const float*)d_in[11];
  const float* bout = (const float*)d_in[12];
  const float* w_t  = (const float*)d_in[13];
  const float* b_t  = (const float*)d_in[14];
  const float* w_o  = (const float*)d_in[15];
  const float* b_o  = (const float*)d_in[16];
  const float* w_c  = (const float*)d_in[17];
  const float* b_c  = (const float*)d_in[18];

  char* ws = (char*)d_ws;
  unsigned short* xn = (unsigned short*)(ws + XN_OFF);
  unsigned short* ys = (unsigned short*)(ws + YS_OFF);
  unsigned short* h0 = (unsigned short*)(ws + H0_OFF);
  unsigned* bar = (unsigned*)(ws + BAR_OFF);
  float* stats = (float*)(ws + ST_OFF);

  // ws is re-poisoned to 0xAA before every launch: zero h0 state + barriers.
  hipMemsetAsync((void*)(ws + H0_OFF), 0, H0_BYTES + BAR_BYTES, stream);

  stats_kernel<<<128, 128, 0, stream>>>(trt, outh, cov, stats);
  norm_kernel<<<(L_ * B_ * CI_) / 256, 256, 0, stream>>>(
      trt, outh, cov, stats, w_t, b_t, w_o, b_o, w_c, b_c, xn);

  rnn_kernel<<<256, 256, 0, stream>>>(xn, ys, h0, bar,
                                      Wih0, Whh0, bih0, bhh0,
                                      Wih1, Whh1, bih1, bhh1);

  out_kernel<<<2560, 64, 0, stream>>>(ys, Wout, bout, w_o, b_o, w_c, b_c,
                                      stats, (float*)d_out);
}

// Round 5
// 3466.949 us; speedup vs baseline: 4.3305x; 1.7122x over previous
//
#include <hip/hip_runtime.h>

// ---------------------------------------------------------------------------
// GNet: RevIN -> 2-layer GRU (B=128, L=512, H=512, I=96) -> proj -> RevIN^-1
// Persistent kernel, 256 blocks x 256 thr (1 block/CU guaranteed), weights in
// VGPRs as bf16 MFMA B-frags, 8 independent batch groups (blockIdx%8), one
// group barrier per timestep.
// R4 post-mortem: 11.3 us/phase. Residual cost = per-phase agent-scope
// ACQ_REL/ACQUIRE (buffer_wbl2 + buffer_inv, whole-L2 ops, x32 blocks) plus
// 32 same-line RMWs serializing at the coherence point.
// R5 fix: NO cache-maintenance ops anywhere in the loop:
//   - h-exchange data uses relaxed AGENT-scope atomics (sc1: straight to the
//     coherence point; L2 never holds these lines) — u32 packed stores
//     (shfl_xor lane pairing), u64 fragment loads.
//   - previous-h for the GRU update is register-carried (same lane wrote it).
//   - barrier: monotonic counter, RELAXED only, split over 8 sub-lines
//     (4 arrivals each); __syncthreads drains vmcnt before arrival.
// ---------------------------------------------------------------------------

typedef __attribute__((ext_vector_type(8))) __bf16 bf16x8;
typedef __attribute__((ext_vector_type(4))) float  f32x4;

constexpr int B_  = 128;
constexpr int L_  = 512;
constexpr int H_  = 512;
constexpr int CI_ = 96;    // 16 treat + 16 outcome + 64 covariate
constexpr float EPSR = 1e-5f;
constexpr unsigned GRP_BLKS = 32;   // blocks per sync group

// ws layout (bytes)
constexpr size_t XN_OFF = 0;                                   // bf16 [L][B][96]
constexpr size_t XN_BYTES = (size_t)L_ * B_ * CI_ * 2;
constexpr size_t YS_OFF = XN_OFF + XN_BYTES;                   // bf16 [L][B][H]
constexpr size_t YS_BYTES = (size_t)L_ * B_ * H_ * 2;
constexpr size_t H0_OFF = YS_OFF + YS_BYTES;                   // bf16 [2][B][H]
constexpr size_t H0_BYTES = (size_t)2 * B_ * H_ * 2;
constexpr size_t BAR_OFF = H0_OFF + H0_BYTES;                  // 8 grp x 8 sub x 128B
constexpr size_t BAR_BYTES = 8 * 8 * 128;
constexpr size_t ST_OFF = BAR_OFF + BAR_BYTES;                 // fp32 stats
// stats float offsets
constexpr int ST_TM = 0, ST_TSD = 2048, ST_OM = 4096, ST_OSD = 6144,
              ST_CM = 8192, ST_CSD = 16384;  // total 24576 floats

__device__ inline unsigned short f2bf(float f) {
  unsigned u = __builtin_bit_cast(unsigned, f);
  u += 0x7fffu + ((u >> 16) & 1u);
  return (unsigned short)(u >> 16);
}
__device__ inline float bf2f(unsigned short h) {
  unsigned u = ((unsigned)h) << 16;
  return __builtin_bit_cast(float, u);
}

union U16x8 { uint4 u4; unsigned long long q[2]; unsigned short s[8]; bf16x8 v; };

__device__ inline bf16x8 load_bf8(const unsigned short* p) {   // cached path
  U16x8 t; t.u4 = *(const uint4*)p; return t.v;
}
// Coherent (agent-scope, cache-bypassing) fragment load: 2 x u64 relaxed.
__device__ inline bf16x8 load_bf8_coh(const unsigned short* p) {
  U16x8 t;
  const unsigned long long* q = (const unsigned long long*)p;
  t.q[0] = __hip_atomic_load(q + 0, __ATOMIC_RELAXED, __HIP_MEMORY_SCOPE_AGENT);
  t.q[1] = __hip_atomic_load(q + 1, __ATOMIC_RELAXED, __HIP_MEMORY_SCOPE_AGENT);
  return t.v;
}
__device__ inline bf16x8 cvt_frag(const float* p) {  // 8 consecutive fp32 -> bf16x8
  U16x8 t;
  float4 a = *(const float4*)p;
  float4 b = *(const float4*)(p + 4);
  t.s[0] = f2bf(a.x); t.s[1] = f2bf(a.y); t.s[2] = f2bf(a.z); t.s[3] = f2bf(a.w);
  t.s[4] = f2bf(b.x); t.s[5] = f2bf(b.y); t.s[6] = f2bf(b.z); t.s[7] = f2bf(b.w);
  return t.v;
}
__device__ inline f32x4 mfma16(bf16x8 a, bf16x8 b, f32x4 c) {
  return __builtin_amdgcn_mfma_f32_16x16x32_bf16(a, b, c, 0, 0, 0);
}
__device__ inline float sigm(float x) {
  x = fminf(fmaxf(x, -30.f), 30.f);
  return 1.f / (1.f + __expf(-x));
}
__device__ inline float tanh_(float x) {
  x = fminf(fmaxf(x, -15.f), 15.f);
  float e = __expf(-2.f * x);
  return (1.f - e) / (1.f + e);
}

// Fence-free group barrier: monotonic counters (no reset -> no race), all
// RELAXED (no buffer_wbl2 / buffer_inv!). Arrival spread over 8 sub-lines.
// Preceding __syncthreads drains each wave's sc1 stores (vmcnt 0) so data is
// at the coherence point before arrival is visible.
__device__ inline void group_bar(unsigned* base, int sub, unsigned target) {
  __syncthreads();
  if (threadIdx.x == 0) {
    __hip_atomic_fetch_add(base + sub * 32, 1u, __ATOMIC_RELAXED,
                           __HIP_MEMORY_SCOPE_AGENT);
    unsigned s;
    do {
      __builtin_amdgcn_s_sleep(1);
      s = 0;
#pragma unroll
      for (int i = 0; i < 8; ++i)
        s += __hip_atomic_load(base + i * 32, __ATOMIC_RELAXED,
                               __HIP_MEMORY_SCOPE_AGENT);
    } while ((int)(s - target) < 0);
  }
  __syncthreads();
}

// ---------------------------------------------------------------------------
// RevIN statistics: mean + std (ddof=1) per (batch, channel), two-pass.
// ---------------------------------------------------------------------------
__global__ void stats_kernel(const float* __restrict__ trt,
                             const float* __restrict__ outh,
                             const float* __restrict__ cov,
                             float* __restrict__ stats) {
  int b = blockIdx.x;
  int ch = threadIdx.x;
  if (ch >= 96) return;
  const float* p; int C; float* mdst; float* sdst; int si;
  if (ch < 16)      { p = trt  + (size_t)b * L_ * 16 + ch;        C = 16; mdst = stats + ST_TM; sdst = stats + ST_TSD; si = b * 16 + ch; }
  else if (ch < 32) { p = outh + (size_t)b * L_ * 16 + (ch - 16); C = 16; mdst = stats + ST_OM; sdst = stats + ST_OSD; si = b * 16 + ch - 16; }
  else              { p = cov  + (size_t)b * L_ * 64 + (ch - 32); C = 64; mdst = stats + ST_CM; sdst = stats + ST_CSD; si = b * 64 + ch - 32; }
  float s = 0.f;
  for (int t = 0; t < L_; ++t) s += p[(size_t)t * C];
  float m = s / (float)L_;
  float q = 0.f;
  for (int t = 0; t < L_; ++t) { float d = p[(size_t)t * C] - m; q += d * d; }
  float sd = sqrtf(q / (float)(L_ - 1));
  mdst[si] = m; sdst[si] = sd;
}

// ---------------------------------------------------------------------------
// Normalize + concat -> xn bf16, layout [t][b][c]
// ---------------------------------------------------------------------------
__global__ void norm_kernel(const float* __restrict__ trt,
                            const float* __restrict__ outh,
                            const float* __restrict__ cov,
                            const float* __restrict__ stats,
                            const float* __restrict__ w_t, const float* __restrict__ b_t,
                            const float* __restrict__ w_o, const float* __restrict__ b_o,
                            const float* __restrict__ w_c, const float* __restrict__ b_c,
                            unsigned short* __restrict__ xn) {
  int idx = blockIdx.x * 256 + threadIdx.x;  // < L*B*96
  int c = idx % CI_;
  int tb = idx / CI_;
  int b = tb % B_;
  int t = tb / B_;
  float v, m, sd, w, bb;
  if (c < 16) {
    v = trt[((size_t)b * L_ + t) * 16 + c];
    m = stats[ST_TM + b * 16 + c]; sd = stats[ST_TSD + b * 16 + c];
    w = w_t[c]; bb = b_t[c];
  } else if (c < 32) {
    int cc = c - 16;
    v = outh[((size_t)b * L_ + t) * 16 + cc];
    m = stats[ST_OM + b * 16 + cc]; sd = stats[ST_OSD + b * 16 + cc];
    w = w_o[cc]; bb = b_o[cc];
  } else {
    int cc = c - 32;
    v = cov[((size_t)b * L_ + t) * 64 + cc];
    m = stats[ST_CM + b * 64 + cc]; sd = stats[ST_CSD + b * 64 + cc];
    w = w_c[cc]; bb = b_c[cc];
  }
  xn[idx] = f2bf((v - m) / (sd + EPSR) * w + bb);
}

// ---------------------------------------------------------------------------
// Persistent GRU kernel. 256 blocks x 256 threads = 4 waves = 2 wave-pairs.
// Group g = blockIdx%8 owns batch tile m0 = g*16; idx = blockIdx>>3 (0..31):
//   idx<16  -> cell0, u-tile = idx*2+sub;  idx>=16 -> cell1.
// Phase t=1..513: cell0: h0(t)=cell(x_t, h0(t-1));
//                 cell1: h1(t-1)=cell(h0(t-1), h1(t-2)); one group barrier.
// h-state traffic is agent-coherent (sc1); prev-h is register-carried.
// ---------------------------------------------------------------------------
template <int ROLE, int NGI, int KI, int NGH, int CH0, bool GATES>
__device__ __forceinline__ void wave_run(
    unsigned* barbase, int subctr,
    float (*exch)[64][4],
    int lane, int u0, int m0,
    const unsigned short* __restrict__ xn,
    unsigned short* __restrict__ ys,
    unsigned short* __restrict__ h0buf,
    const float* __restrict__ WI, const float* __restrict__ WH,
    const float* __restrict__ bi, const float* __restrict__ bh) {
  const int quad = lane >> 4;
  const int l16 = lane & 15;
  const int b = m0 + l16;      // A-fragment row (batch)
  const int urow = u0 + l16;   // weight row within gate block / output column

  bf16x8 BGI[3][NGI > 0 ? NGI : 1];
  bf16x8 BGH[3][NGH > 0 ? NGH : 1];
  if (NGI > 0) {
#pragma unroll
    for (int g = 0; g < 3; ++g)
#pragma unroll
      for (int c = 0; c < NGI; ++c)
        BGI[g][c] = cvt_frag(WI + (size_t)(g * H_ + urow) * KI + 32 * c + quad * 8);
  }
  if (NGH > 0) {
#pragma unroll
    for (int g = 0; g < 3; ++g)
#pragma unroll
      for (int c = 0; c < NGH; ++c)
        BGH[g][c] = cvt_frag(WH + (size_t)(g * H_ + urow) * H_ + 32 * (CH0 + c) + quad * 8);
  }
  float bi_[3] = {0.f, 0.f, 0.f}, bh_[3] = {0.f, 0.f, 0.f};
  if (GATES) {
#pragma unroll
    for (int g = 0; g < 3; ++g) { bi_[g] = bi[g * H_ + urow]; bh_[g] = bh[g * H_ + urow]; }
  }
  // register-carried previous h at (m0+quad*4+r, urow) — this lane wrote it.
  float hp[4] = {0.f, 0.f, 0.f, 0.f};

  for (int t = 1; t <= 513; ++t) {
    const bool active = (ROLE == 0) ? (t <= 512) : (t >= 2);
    f32x4 agi[3], agh[3];
#pragma unroll
    for (int g = 0; g < 3; ++g) {
      agi[g] = (f32x4){0.f, 0.f, 0.f, 0.f};
      agh[g] = (f32x4){0.f, 0.f, 0.f, 0.f};
    }
    if (active) {
      if (NGI > 0) {
        if (ROLE == 0) {
          const unsigned short* Agi = xn + ((size_t)(t - 1) * B_ + b) * CI_;
#pragma unroll
          for (int c = 0; c < NGI; ++c) {
            bf16x8 a = load_bf8(Agi + 32 * c + quad * 8);   // cached: xn is const
            agi[0] = mfma16(a, BGI[0][c], agi[0]);
            agi[1] = mfma16(a, BGI[1][c], agi[1]);
            agi[2] = mfma16(a, BGI[2][c], agi[2]);
          }
        } else {
          const unsigned short* Agi =
              h0buf + (size_t)((t - 1) & 1) * B_ * H_ + (size_t)b * H_;
#pragma unroll
          for (int c = 0; c < NGI; ++c) {
            bf16x8 a = load_bf8_coh(Agi + 32 * c + quad * 8);
            agi[0] = mfma16(a, BGI[0][c], agi[0]);
            agi[1] = mfma16(a, BGI[1][c], agi[1]);
            agi[2] = mfma16(a, BGI[2][c], agi[2]);
          }
        }
      }
      if (NGH > 0) {
        bool gh_ok = (ROLE == 0) || (t >= 3);
        if (gh_ok) {
          const unsigned short* Agh = (ROLE == 0)
              ? h0buf + (size_t)((t - 1) & 1) * B_ * H_ + (size_t)b * H_
              : ys + (size_t)(t - 3) * B_ * H_ + (size_t)b * H_;
#pragma unroll
          for (int c = 0; c < NGH; ++c) {
            bf16x8 a = load_bf8_coh(Agh + 32 * (CH0 + c) + quad * 8);
            agh[0] = mfma16(a, BGH[0][c], agh[0]);
            agh[1] = mfma16(a, BGH[1][c], agh[1]);
            agh[2] = mfma16(a, BGH[2][c], agh[2]);
          }
        }
      }
    }
    if (!GATES) {
      // producer wave: publish gh partials to LDS (zeros when inactive)
#pragma unroll
      for (int g = 0; g < 3; ++g)
#pragma unroll
        for (int r = 0; r < 4; ++r) exch[g][lane][r] = agh[g][r];
      __syncthreads();
    } else {
      __syncthreads();
      if (active) {
#pragma unroll
        for (int g = 0; g < 3; ++g)
#pragma unroll
          for (int r = 0; r < 4; ++r) agh[g][r] += exch[g][lane][r];
        unsigned us[4];
#pragma unroll
        for (int r = 0; r < 4; ++r) {
          float rr = sigm(agi[0][r] + bi_[0] + agh[0][r] + bh_[0]);
          float zz = sigm(agi[1][r] + bi_[1] + agh[1][r] + bh_[1]);
          float nn = tanh_(agi[2][r] + bi_[2] + rr * (agh[2][r] + bh_[2]));
          float hv = (1.f - zz) * nn + zz * hp[r];
          hp[r] = hv;
          us[r] = f2bf(hv);
        }
        // pack 2 bf16 along u (adjacent l16 lanes) -> u32 coherent stores.
        unsigned sh0 = (unsigned)__shfl_xor((int)us[0], 1);
        unsigned sh1 = (unsigned)__shfl_xor((int)us[1], 1);
        unsigned sh2 = (unsigned)__shfl_xor((int)us[2], 1);
        unsigned sh3 = (unsigned)__shfl_xor((int)us[3], 1);
        bool odd = (l16 & 1) != 0;
        unsigned ownA = odd ? us[2] : us[0];
        unsigned prtA = odd ? sh2 : sh0;
        unsigned ownB = odd ? us[3] : us[1];
        unsigned prtB = odd ? sh3 : sh1;
        unsigned pkA = odd ? ((prtA & 0xffffu) | (ownA << 16))
                           : ((ownA & 0xffffu) | (prtA << 16));
        unsigned pkB = odd ? ((prtB & 0xffffu) | (ownB << 16))
                           : ((ownB & 0xffffu) | (prtB << 16));
        int rA = odd ? 2 : 0;
        unsigned short* outp = (ROLE == 0)
            ? h0buf + (size_t)(t & 1) * B_ * H_
            : ys + (size_t)(t - 2) * B_ * H_;
        unsigned* dst = (unsigned*)outp;
        size_t idxA = (size_t)(m0 + quad * 4 + rA) * (H_ / 2)
                      + ((u0 + (l16 & ~1)) >> 1);
        __hip_atomic_store(dst + idxA, pkA, __ATOMIC_RELAXED,
                           __HIP_MEMORY_SCOPE_AGENT);
        __hip_atomic_store(dst + idxA + (H_ / 2), pkB, __ATOMIC_RELAXED,
                           __HIP_MEMORY_SCOPE_AGENT);
      }
    }
    group_bar(barbase, subctr, (unsigned)t * GRP_BLKS);
  }
}

__launch_bounds__(256, 1)
__global__ void rnn_kernel(const unsigned short* __restrict__ xn,
                           unsigned short* __restrict__ ys,
                           unsigned short* __restrict__ h0buf,
                           unsigned* __restrict__ bar,
                           const float* __restrict__ Wih0, const float* __restrict__ Whh0,
                           const float* __restrict__ bih0, const float* __restrict__ bhh0,
                           const float* __restrict__ Wih1, const float* __restrict__ Whh1,
                           const float* __restrict__ bih1, const float* __restrict__ bhh1) {
  __shared__ float exch[2][3][64][4];

  const int grp = blockIdx.x & 7;        // batch-tile / sync group
  const int idx = blockIdx.x >> 3;       // 0..31 within group
  unsigned* barbase = bar + grp * (8 * 32);   // 8 sub-lines x 128B per group
  const int subctr = idx & 7;
  const int m0 = grp * 16;

  const int wave = threadIdx.x >> 6;
  const int lane = threadIdx.x & 63;
  const int sub = wave >> 1;   // which wave-pair in this block
  const int wr = wave & 1;     // 0 = GATES consumer, 1 = producer

  if (idx < 16) {
    int u0 = (idx * 2 + sub) * 16;
    if (wr == 0)
      wave_run<0, 3, CI_, 8, 0, true>(barbase, subctr, exch[sub], lane, u0, m0,
                                      xn, ys, h0buf, Wih0, Whh0, bih0, bhh0);
    else
      wave_run<0, 0, CI_, 8, 8, false>(barbase, subctr, exch[sub], lane, u0, m0,
                                       xn, ys, h0buf, Wih0, Whh0, bih0, bhh0);
  } else {
    int u0 = ((idx - 16) * 2 + sub) * 16;
    if (wr == 0)
      wave_run<1, 16, H_, 0, 0, true>(barbase, subctr, exch[sub], lane, u0, m0,
                                      xn, ys, h0buf, Wih1, Whh1, bih1, bhh1);
    else
      wave_run<1, 0, H_, 16, 0, false>(barbase, subctr, exch[sub], lane, u0, m0,
                                       xn, ys, h0buf, Wih1, Whh1, bih1, bhh1);
  }
}

// ---------------------------------------------------------------------------
// Output projection (65536 x 80, K=512) + inverse RevIN, MFMA.
// grid = 512 m-chunks * 5 n-tiles = 2560 blocks x 64 threads (1 wave).
// ---------------------------------------------------------------------------
__global__ void out_kernel(const unsigned short* __restrict__ ys,
                           const float* __restrict__ Wout, const float* __restrict__ bout,
                           const float* __restrict__ w_o, const float* __restrict__ b_o,
                           const float* __restrict__ w_c, const float* __restrict__ b_c,
                           const float* __restrict__ stats,
                           float* __restrict__ dout) {
  int lane = threadIdx.x;
  int quad = lane >> 4, l16 = lane & 15;
  int nb = blockIdx.x % 5, mc = blockIdx.x / 5;
  int ch = nb * 16 + l16;

  bf16x8 BW[16];
#pragma unroll
  for (int c = 0; c < 16; ++c)
    BW[c] = cvt_frag(Wout + (size_t)ch * 512 + 32 * c + quad * 8);
  float bo = bout[ch];
  float rb, rw; const float* mm; const float* ss; int cs, cidx;
  if (ch < 16) { rb = b_o[ch]; rw = w_o[ch]; mm = stats + ST_OM; ss = stats + ST_OSD; cs = 16; cidx = ch; }
  else         { rb = b_c[ch - 16]; rw = w_c[ch - 16]; mm = stats + ST_CM; ss = stats + ST_CSD; cs = 64; cidx = ch - 16; }

  for (int i = 0; i < 8; ++i) {
    int mt = mc * 8 + i;
    const unsigned short* A = ys + (size_t)(mt * 16 + l16) * 512;
    f32x4 acc = {0.f, 0.f, 0.f, 0.f};
#pragma unroll
    for (int c = 0; c < 16; ++c)
      acc = mfma16(load_bf8(A + 32 * c + quad * 8), BW[c], acc);
#pragma unroll
    for (int r = 0; r < 4; ++r) {
      int rr = mt * 16 + quad * 4 + r;
      int t = rr >> 7;
      int b = rr & 127;
      float m = mm[b * cs + cidx], sd = ss[b * cs + cidx];
      float v = (acc[r] + bo - rb) / rw * (sd + EPSR) + m;
      size_t off = (ch < 16)
          ? ((size_t)b * 8192 + (size_t)t * 16 + ch)
          : ((size_t)1048576 + (size_t)b * 32768 + (size_t)t * 64 + (ch - 16));
      dout[off] = v;
    }
  }
}

// ---------------------------------------------------------------------------
extern "C" void kernel_launch(void* const* d_in, const int* in_sizes, int n_in,
                              void* d_out, int out_size, void* d_ws, size_t ws_size,
                              hipStream_t stream) {
  const float* cov  = (const float*)d_in[0];
  const float* trt  = (const float*)d_in[1];
  const float* outh = (const float*)d_in[2];
  const float* Wih0 = (const float*)d_in[3];
  const float* Whh0 = (const float*)d_in[4];
  const float* bih0 = (const float*)d_in[5];
  const float* bhh0 = (const float*)d_in[6];
  const float* Wih1 = (const float*)d_in[7];
  const float* Whh1 = (const float*)d_in[8];
  const float* bih1 = (const float*)d_in[9];
  const float* bhh1 = (const float*)d_in[10];
  const float* Wout = (const float*)d_in[11];
  const float* bout = (const float*)d_in[12];
  const float* w_t  = (const float*)d_in[13];
  const float* b_t  = (const float*)d_in[14];
  const float* w_o  = (const float*)d_in[15];
  const float* b_o  = (const float*)d_in[16];
  const float* w_c  = (const float*)d_in[17];
  const float* b_c  = (const float*)d_in[18];

  char* ws = (char*)d_ws;
  unsigned short* xn = (unsigned short*)(ws + XN_OFF);
  unsigned short* ys = (unsigned short*)(ws + YS_OFF);
  unsigned short* h0 = (unsigned short*)(ws + H0_OFF);
  unsigned* bar = (unsigned*)(ws + BAR_OFF);
  float* stats = (float*)(ws + ST_OFF);

  // ws is re-poisoned to 0xAA before every launch: zero h0 state + barriers.
  hipMemsetAsync((void*)(ws + H0_OFF), 0, H0_BYTES + BAR_BYTES, stream);

  stats_kernel<<<128, 128, 0, stream>>>(trt, outh, cov, stats);
  norm_kernel<<<(L_ * B_ * CI_) / 256, 256, 0, stream>>>(
      trt, outh, cov, stats, w_t, b_t, w_o, b_o, w_c, b_c, xn);

  rnn_kernel<<<256, 256, 0, stream>>>(xn, ys, h0, bar,
                                      Wih0, Whh0, bih0, bhh0,
                                      Wih1, Whh1, bih1, bhh1);

  out_kernel<<<2560, 64, 0, stream>>>(ys, Wout, bout, w_o, b_o, w_c, b_c,
                                      stats, (float*)d_out);
}